// Round 1
// baseline (320.405 us; speedup 1.0000x reference)
//
#include <hip/hip_runtime.h>

#define AS1 __attribute__((address_space(1)))
#define AS3 __attribute__((address_space(3)))

using f32x4 = __attribute__((ext_vector_type(4))) float;
using s16x8 = __attribute__((ext_vector_type(8))) short;
using u16x4 = __attribute__((ext_vector_type(4))) unsigned short;

__device__ __forceinline__ unsigned short f2bf(float f) {
  union { float f; unsigned u; } v; v.f = f;
  unsigned u = v.u;
  return (unsigned short)((u + 0x7FFFu + ((u >> 16) & 1u)) >> 16);  // RNE
}

__device__ __forceinline__ void load_lds16(const void* g, void* l) {
  __builtin_amdgcn_global_load_lds((const AS1 void*)g, (AS3 void*)l, 16, 0, 0);
}

// ---------------- fp32 -> bf16 cast (x) ----------------
__global__ __launch_bounds__(256) void f32_to_bf16_kernel(const float* __restrict__ in,
                                                          unsigned short* __restrict__ out,
                                                          int n4) {
  int i = blockIdx.x * 256 + threadIdx.x;
  if (i < n4) {
    float4 v = ((const float4*)in)[i];
    u16x4 o;
    o.x = f2bf(v.x); o.y = f2bf(v.y); o.z = f2bf(v.z); o.w = f2bf(v.w);
    ((u16x4*)out)[i] = o;
  }
}

// ---------------- fp32 [R][C] -> bf16 [C][R] transpose (weights) ----------------
__global__ __launch_bounds__(256) void transpose_f32_bf16(const float* __restrict__ in,
                                                          unsigned short* __restrict__ out,
                                                          int R, int C) {
  __shared__ float tile[32][33];
  int x = blockIdx.x * 32 + threadIdx.x;
  int y0 = blockIdx.y * 32;
  for (int j = threadIdx.y; j < 32; j += 8)
    tile[j][threadIdx.x] = in[(size_t)(y0 + j) * C + x];
  __syncthreads();
  int x2 = blockIdx.y * 32 + threadIdx.x;
  int y2 = blockIdx.x * 32;
  for (int j = threadIdx.y; j < 32; j += 8)
    out[(size_t)(y2 + j) * R + x2] = f2bf(tile[threadIdx.x][j]);
}

// ---------------- bf16 GEMM: C[M,N] = A[M,K] * Bt[N,K]^T ----------------
// m97 structure: 128x128 tile, BK=32, 256 threads (4 waves, each 64x64),
// global_load_lds width-16 staging, 16x16x32 bf16 MFMA.
template <bool OUT_BF16>
__global__ __launch_bounds__(256) void gemm_bt(const unsigned short* __restrict__ A,
                                               const unsigned short* __restrict__ Bt,
                                               void* __restrict__ Cout,
                                               int M, int N, int K) {
  __shared__ unsigned short As[128 * 32];
  __shared__ unsigned short Bs[128 * 32];
  const int tid = threadIdx.x;
  const int wave = tid >> 6, lane = tid & 63;
  const int l15 = lane & 15, quad = lane >> 4;
  const int wm = wave & 1, wn = wave >> 1;
  const int bm = blockIdx.y, bn = blockIdx.x;

  f32x4 acc[4][4] = {};

  const int c0 = wave * 128 + lane;  // chunk id; lds dest = base + lane*16 (wave-uniform base)
  for (int k0 = 0; k0 < K; k0 += 32) {
    __syncthreads();
#pragma unroll
    for (int s = 0; s < 2; ++s) {
      int c = c0 + s * 64;
      int row = c >> 2, kc = (c & 3) * 8;  // 32 elems/row = 4 chunks of 8 bf16
      load_lds16(A + (size_t)(bm * 128 + row) * K + k0 + kc, As + c * 8);
      load_lds16(Bt + (size_t)(bn * 128 + row) * K + k0 + kc, Bs + c * 8);
    }
    __syncthreads();
    s16x8 af[4], bfr[4];
#pragma unroll
    for (int i = 0; i < 4; ++i) {
      af[i]  = *(const s16x8*)(As + (wm * 64 + i * 16 + l15) * 32 + quad * 8);
      bfr[i] = *(const s16x8*)(Bs + (wn * 64 + i * 16 + l15) * 32 + quad * 8);
    }
#pragma unroll
    for (int i = 0; i < 4; ++i)
#pragma unroll
      for (int j = 0; j < 4; ++j)
        acc[i][j] = __builtin_amdgcn_mfma_f32_16x16x32_bf16(af[i], bfr[j], acc[i][j], 0, 0, 0);
  }

  // C/D layout: col = lane&15, row = quad*4 + reg (verified m89/m91)
  const int row0 = bm * 128 + wm * 64 + quad * 4;
  const int col0 = bn * 128 + wn * 64 + l15;
#pragma unroll
  for (int i = 0; i < 4; ++i)
#pragma unroll
    for (int j = 0; j < 4; ++j)
#pragma unroll
      for (int r = 0; r < 4; ++r) {
        size_t idx = (size_t)(row0 + i * 16 + r) * N + (col0 + j * 16);
        if constexpr (OUT_BF16) ((unsigned short*)Cout)[idx] = f2bf(acc[i][j][r]);
        else                    ((float*)Cout)[idx] = acc[i][j][r];
      }
}

// ---------------- flash attention ----------------
// qkv: bf16 [B*S, 3072]; q at col h*64, k at 1024+h*64, v at 2048+h*64.
// grid: (S/64, B*H). 256 threads = 4 waves; wave w owns q rows [q0+16w, q0+16w+16).
__global__ __launch_bounds__(256) void attn_kernel(const unsigned short* __restrict__ qkv,
                                                   unsigned short* __restrict__ Y) {
  __shared__ unsigned short Qs[64 * 64];
  __shared__ unsigned short Ks[64 * 64];
  __shared__ unsigned short Vs[64 * 64];
  __shared__ unsigned short Ps[4][16 * 64];
  const int tid = threadIdx.x;
  const int wave = tid >> 6, lane = tid & 63;
  const int l15 = lane & 15, quad = lane >> 4;
  const int bh = blockIdx.y, b = bh >> 4, h = bh & 15;
  const int q0 = blockIdx.x * 64;
  const size_t base = (size_t)b * 2048 * 3072 + h * 64;

  // stage Q tile [64][64]: 512 chunks of 16B, 2 per thread
#pragma unroll
  for (int s = 0; s < 2; ++s) {
    int c = tid + s * 256;
    int row = c >> 3, kc = (c & 7) * 8;  // 64 elems/row = 8 chunks
    load_lds16(qkv + base + (size_t)(q0 + row) * 3072 + kc, Qs + c * 8);
  }
  __syncthreads();
  // Q A-fragments (A[m=lane&15][k=quad*8+j]), K-dim 64 = 2 chunks; held in regs all loop
  s16x8 qf[2];
  qf[0] = *(const s16x8*)(Qs + (wave * 16 + l15) * 64 + quad * 8);
  qf[1] = *(const s16x8*)(Qs + (wave * 16 + l15) * 64 + 32 + quad * 8);

  f32x4 o[4] = {};
  float m_i[4] = {-1e30f, -1e30f, -1e30f, -1e30f};
  float l_i[4] = {0.f, 0.f, 0.f, 0.f};

  for (int j0 = 0; j0 <= q0; j0 += 64) {
    __syncthreads();
#pragma unroll
    for (int s = 0; s < 2; ++s) {
      int c = tid + s * 256;
      int row = c >> 3, kc = (c & 7) * 8;
      load_lds16(qkv + base + (size_t)(j0 + row) * 3072 + 1024 + kc, Ks + c * 8);
      load_lds16(qkv + base + (size_t)(j0 + row) * 3072 + 2048 + kc, Vs + c * 8);
    }
    __syncthreads();

    // S = Q K^T : B-operand fragment of K^T == A-layout read of K rows
    f32x4 s[4];
#pragma unroll
    for (int nt = 0; nt < 4; ++nt) {
      s16x8 kf0 = *(const s16x8*)(Ks + (nt * 16 + l15) * 64 + quad * 8);
      s16x8 kf1 = *(const s16x8*)(Ks + (nt * 16 + l15) * 64 + 32 + quad * 8);
      f32x4 z = {};
      z = __builtin_amdgcn_mfma_f32_16x16x32_bf16(qf[0], kf0, z, 0, 0, 0);
      z = __builtin_amdgcn_mfma_f32_16x16x32_bf16(qf[1], kf1, z, 0, 0, 0);
      s[nt] = z;
    }

    // scale + causal mask: lane holds S[row=quad*4+r][key=nt*16+l15]
    const int qrow = q0 + wave * 16 + quad * 4;
#pragma unroll
    for (int nt = 0; nt < 4; ++nt) {
      int key = j0 + nt * 16 + l15;
#pragma unroll
      for (int r = 0; r < 4; ++r)
        s[nt][r] = (key <= qrow + r) ? s[nt][r] * 0.125f : -1e30f;
    }

    // online softmax: row reduce across the 16 lanes of the quad
    float tmax[4], alpha[4], rsum[4];
#pragma unroll
    for (int r = 0; r < 4; ++r)
      tmax[r] = fmaxf(fmaxf(s[0][r], s[1][r]), fmaxf(s[2][r], s[3][r]));
#pragma unroll
    for (int off = 1; off < 16; off <<= 1)
#pragma unroll
      for (int r = 0; r < 4; ++r)
        tmax[r] = fmaxf(tmax[r], __shfl_xor(tmax[r], off, 64));
#pragma unroll
    for (int r = 0; r < 4; ++r) {
      float mn = fmaxf(m_i[r], tmax[r]);
      alpha[r] = __expf(m_i[r] - mn);
      m_i[r] = mn;
      rsum[r] = 0.f;
    }
#pragma unroll
    for (int nt = 0; nt < 4; ++nt)
#pragma unroll
      for (int r = 0; r < 4; ++r) {
        float p = __expf(s[nt][r] - m_i[r]);
        s[nt][r] = p;
        rsum[r] += p;
      }
#pragma unroll
    for (int off = 1; off < 16; off <<= 1)
#pragma unroll
      for (int r = 0; r < 4; ++r)
        rsum[r] += __shfl_xor(rsum[r], off, 64);
#pragma unroll
    for (int r = 0; r < 4; ++r)
      l_i[r] = l_i[r] * alpha[r] + rsum[r];
#pragma unroll
    for (int dt = 0; dt < 4; ++dt)
#pragma unroll
      for (int r = 0; r < 4; ++r)
        o[dt][r] *= alpha[r];

    // P: C-layout -> A-layout via LDS round-trip (m120 pattern)
    unsigned short* Pw = &Ps[wave][0];
#pragma unroll
    for (int nt = 0; nt < 4; ++nt)
#pragma unroll
      for (int r = 0; r < 4; ++r)
        Pw[(quad * 4 + r) * 64 + nt * 16 + l15] = f2bf(s[nt][r]);
    __syncthreads();

    s16x8 pf[2];
    pf[0] = *(const s16x8*)(Pw + l15 * 64 + quad * 8);
    pf[1] = *(const s16x8*)(Pw + l15 * 64 + 32 + quad * 8);
    // PV: B-operand = V[k][d], strided scalar LDS reads (correctness-first)
#pragma unroll
    for (int dt = 0; dt < 4; ++dt) {
#pragma unroll
      for (int kk = 0; kk < 2; ++kk) {
        s16x8 vf;
#pragma unroll
        for (int jj = 0; jj < 8; ++jj)
          vf[jj] = (short)Vs[(kk * 32 + quad * 8 + jj) * 64 + dt * 16 + l15];
        o[dt] = __builtin_amdgcn_mfma_f32_16x16x32_bf16(pf[kk], vf, o[dt], 0, 0, 0);
      }
    }
  }

#pragma unroll
  for (int r = 0; r < 4; ++r)
    l_i[r] = 1.0f / l_i[r];
  const size_t yrow = (size_t)(b * 2048 + q0 + wave * 16 + quad * 4);
#pragma unroll
  for (int dt = 0; dt < 4; ++dt)
#pragma unroll
    for (int r = 0; r < 4; ++r)
      Y[(yrow + r) * 1024 + h * 64 + dt * 16 + l15] = f2bf(o[dt][r] * l_i[r]);
}

extern "C" void kernel_launch(void* const* d_in, const int* in_sizes, int n_in,
                              void* d_out, int out_size, void* d_ws, size_t ws_size,
                              hipStream_t stream) {
  const float* x      = (const float*)d_in[0];  // [2,2048,1024]
  const float* w_qkv  = (const float*)d_in[1];  // [1024,3072]
  const float* w_proj = (const float*)d_in[2];  // [1024,1024]
  char* ws = (char*)d_ws;
  unsigned short* xb     = (unsigned short*)(ws);                      //  8 MiB [4096,1024]
  unsigned short* wqkvT  = (unsigned short*)(ws + (size_t)(8  << 20)); //  6 MiB [3072,1024]
  unsigned short* wprojT = (unsigned short*)(ws + (size_t)(14 << 20)); //  2 MiB [1024,1024]
  unsigned short* qkv    = (unsigned short*)(ws + (size_t)(16 << 20)); // 24 MiB [4096,3072]
  unsigned short* y      = (unsigned short*)(ws + (size_t)(40 << 20)); //  8 MiB [4096,1024]

  f32_to_bf16_kernel<<<4096, 256, 0, stream>>>(x, xb, 1048576);
  transpose_f32_bf16<<<dim3(96, 32), dim3(32, 8), 0, stream>>>(w_qkv, wqkvT, 1024, 3072);
  transpose_f32_bf16<<<dim3(32, 32), dim3(32, 8), 0, stream>>>(w_proj, wprojT, 1024, 1024);
  gemm_bt<true><<<dim3(24, 32), 256, 0, stream>>>(xb, wqkvT, qkv, 4096, 3072, 1024);
  attn_kernel<<<dim3(32, 32), 256, 0, stream>>>(qkv, y);
  gemm_bt<false><<<dim3(8, 32), 256, 0, stream>>>(y, wprojT, d_out, 4096, 1024, 1024);
}

// Round 2
// 275.179 us; speedup vs baseline: 1.1644x; 1.1644x over previous
//
#include <hip/hip_runtime.h>

#define AS1 __attribute__((address_space(1)))
#define AS3 __attribute__((address_space(3)))

using f32x4 = __attribute__((ext_vector_type(4))) float;
using s16x8 = __attribute__((ext_vector_type(8))) short;
using u16x4 = __attribute__((ext_vector_type(4))) unsigned short;

__device__ __forceinline__ unsigned short f2bf(float f) {
  union { float f; unsigned u; } v; v.f = f;
  unsigned u = v.u;
  return (unsigned short)((u + 0x7FFFu + ((u >> 16) & 1u)) >> 16);  // RNE
}

__device__ __forceinline__ void load_lds16(const void* g, void* l) {
  __builtin_amdgcn_global_load_lds((const AS1 void*)g, (AS3 void*)l, 16, 0, 0);
}

// ---------------- fp32 -> bf16 cast (x) ----------------
__global__ __launch_bounds__(256) void f32_to_bf16_kernel(const float* __restrict__ in,
                                                          unsigned short* __restrict__ out,
                                                          int n4) {
  int i = blockIdx.x * 256 + threadIdx.x;
  if (i < n4) {
    float4 v = ((const float4*)in)[i];
    u16x4 o;
    o.x = f2bf(v.x); o.y = f2bf(v.y); o.z = f2bf(v.z); o.w = f2bf(v.w);
    ((u16x4*)out)[i] = o;
  }
}

// ---------------- fp32 [R][C] -> bf16 [C][R] transpose (weights) ----------------
__global__ __launch_bounds__(256) void transpose_f32_bf16(const float* __restrict__ in,
                                                          unsigned short* __restrict__ out,
                                                          int R, int C) {
  __shared__ float tile[32][33];
  int x = blockIdx.x * 32 + threadIdx.x;
  int y0 = blockIdx.y * 32;
  for (int j = threadIdx.y; j < 32; j += 8)
    tile[j][threadIdx.x] = in[(size_t)(y0 + j) * C + x];
  __syncthreads();
  int x2 = blockIdx.y * 32 + threadIdx.x;
  int y2 = blockIdx.x * 32;
  for (int j = threadIdx.y; j < 32; j += 8)
    out[(size_t)(y2 + j) * R + x2] = f2bf(tile[threadIdx.x][j]);
}

// ---------------- V transpose: qkv V block [s][d] -> Vt[b][h][d][s] ----------------
__global__ __launch_bounds__(256) void transpose_v(const unsigned short* __restrict__ qkv,
                                                   unsigned short* __restrict__ Vt) {
  __shared__ unsigned short tile[64][65];  // +1 pad breaks bank alignment
  const int tid = threadIdx.x;
  const int bh = blockIdx.y, b = bh >> 4, h = bh & 15;
  const int s0 = blockIdx.x * 64;
#pragma unroll
  for (int it = 0; it < 2; ++it) {
    int c = tid + it * 256;
    int row = c >> 3, cc = c & 7;
    s16x8 v = *(const s16x8*)(qkv + (size_t)(b * 2048 + s0 + row) * 3072 + 2048 + h * 64 + cc * 8);
#pragma unroll
    for (int j = 0; j < 8; ++j) tile[row][cc * 8 + j] = (unsigned short)v[j];
  }
  __syncthreads();
#pragma unroll
  for (int it = 0; it < 2; ++it) {
    int c = tid + it * 256;
    int d = c >> 3, sc = c & 7;
    s16x8 o;
#pragma unroll
    for (int j = 0; j < 8; ++j) o[j] = (short)tile[sc * 8 + j][d];
    *(s16x8*)(Vt + (size_t)bh * 64 * 2048 + (size_t)d * 2048 + s0 + sc * 8) = o;
  }
}

// ---------------- bf16 GEMM: C[M,N] = A[M,K] * Bt[N,K]^T (m97 structure) ----------------
template <bool OUT_BF16>
__global__ __launch_bounds__(256) void gemm_bt(const unsigned short* __restrict__ A,
                                               const unsigned short* __restrict__ Bt,
                                               void* __restrict__ Cout,
                                               int M, int N, int K) {
  __shared__ unsigned short As[128 * 32];
  __shared__ unsigned short Bs[128 * 32];
  const int tid = threadIdx.x;
  const int wave = tid >> 6, lane = tid & 63;
  const int l15 = lane & 15, quad = lane >> 4;
  const int wm = wave & 1, wn = wave >> 1;
  const int bm = blockIdx.y, bn = blockIdx.x;

  f32x4 acc[4][4] = {};

  const int c0 = wave * 128 + lane;
  for (int k0 = 0; k0 < K; k0 += 32) {
    __syncthreads();
#pragma unroll
    for (int s = 0; s < 2; ++s) {
      int c = c0 + s * 64;
      int row = c >> 2, kc = (c & 3) * 8;
      load_lds16(A + (size_t)(bm * 128 + row) * K + k0 + kc, As + c * 8);
      load_lds16(Bt + (size_t)(bn * 128 + row) * K + k0 + kc, Bs + c * 8);
    }
    __syncthreads();
    s16x8 af[4], bfr[4];
#pragma unroll
    for (int i = 0; i < 4; ++i) {
      af[i]  = *(const s16x8*)(As + (wm * 64 + i * 16 + l15) * 32 + quad * 8);
      bfr[i] = *(const s16x8*)(Bs + (wn * 64 + i * 16 + l15) * 32 + quad * 8);
    }
#pragma unroll
    for (int i = 0; i < 4; ++i)
#pragma unroll
      for (int j = 0; j < 4; ++j)
        acc[i][j] = __builtin_amdgcn_mfma_f32_16x16x32_bf16(af[i], bfr[j], acc[i][j], 0, 0, 0);
  }

  const int row0 = bm * 128 + wm * 64 + quad * 4;
  const int col0 = bn * 128 + wn * 64 + l15;
#pragma unroll
  for (int i = 0; i < 4; ++i)
#pragma unroll
    for (int j = 0; j < 4; ++j)
#pragma unroll
      for (int r = 0; r < 4; ++r) {
        size_t idx = (size_t)(row0 + i * 16 + r) * N + (col0 + j * 16);
        if constexpr (OUT_BF16) ((unsigned short*)Cout)[idx] = f2bf(acc[i][j][r]);
        else                    ((float*)Cout)[idx] = acc[i][j][r];
      }
}

// ---------------- flash attention, swizzled LDS ----------------
// Tiles are [64 rows][8 chunks of 8 bf16]; logical chunk cc of row r is stored at
// physical chunk cc^(r&7) (swizzle applied on the *global source* address since
// global_load_lds's LDS dest is wave-uniform-base + lane*16). All fragment-read
// rows are == l15 (mod 8), so reads XOR with sx = l15&7 -> 64 lanes spread
// uniformly over 32 banks (8 dwords/bank = b128 floor).
__global__ __launch_bounds__(256) void attn_kernel(const unsigned short* __restrict__ qkv,
                                                   const unsigned short* __restrict__ Vt,
                                                   unsigned short* __restrict__ Y) {
  __shared__ unsigned short Qs[64 * 64];
  __shared__ unsigned short Ks[64 * 64];
  __shared__ unsigned short Vs[64 * 64];  // holds Vt tile: rows = d, cols = keys
  __shared__ unsigned short Ps[4][16 * 64];
  const int tid = threadIdx.x;
  const int wave = tid >> 6, lane = tid & 63;
  const int l15 = lane & 15, quad = lane >> 4;
  const int sx = l15 & 7;
  const int bh = blockIdx.y, b = bh >> 4, h = bh & 15;
  const int q0 = (gridDim.x - 1 - blockIdx.x) * 64;  // longest-running blocks first
  const size_t base = (size_t)b * 2048 * 3072 + h * 64;
  const size_t vbase = (size_t)bh * 64 * 2048;

  // stage Q tile (swizzled)
#pragma unroll
  for (int s = 0; s < 2; ++s) {
    int c = tid + s * 256;
    int row = c >> 3, cc = c & 7;
    int kc = (cc ^ (row & 7)) * 8;
    load_lds16(qkv + base + (size_t)(q0 + row) * 3072 + kc, Qs + c * 8);
  }
  __syncthreads();
  const int qr = wave * 16 + l15;
  s16x8 qf[2];
  qf[0] = *(const s16x8*)(Qs + qr * 64 + ((quad    ) ^ sx) * 8);
  qf[1] = *(const s16x8*)(Qs + qr * 64 + ((quad + 4) ^ sx) * 8);

  f32x4 o[4] = {};
  float m_i[4] = {-1e30f, -1e30f, -1e30f, -1e30f};
  float l_i[4] = {0.f, 0.f, 0.f, 0.f};
  // softmax in exp2 domain; fold 1/sqrt(64)*log2(e) into the scale
  const float kScale = 0.125f * 1.44269504f;

  for (int j0 = 0; j0 <= q0; j0 += 64) {
    __syncthreads();
#pragma unroll
    for (int s = 0; s < 2; ++s) {
      int c = tid + s * 256;
      int row = c >> 3, cc = c & 7;
      int kc = (cc ^ (row & 7)) * 8;
      load_lds16(qkv + base + (size_t)(j0 + row) * 3072 + 1024 + kc, Ks + c * 8);
      load_lds16(Vt + vbase + (size_t)row * 2048 + j0 + kc, Vs + c * 8);
    }
    __syncthreads();

    // S = Q K^T
    f32x4 s[4];
#pragma unroll
    for (int nt = 0; nt < 4; ++nt) {
      const int kr = nt * 16 + l15;
      s16x8 kf0 = *(const s16x8*)(Ks + kr * 64 + ((quad    ) ^ sx) * 8);
      s16x8 kf1 = *(const s16x8*)(Ks + kr * 64 + ((quad + 4) ^ sx) * 8);
      f32x4 z = {};
      z = __builtin_amdgcn_mfma_f32_16x16x32_bf16(qf[0], kf0, z, 0, 0, 0);
      z = __builtin_amdgcn_mfma_f32_16x16x32_bf16(qf[1], kf1, z, 0, 0, 0);
      s[nt] = z;
    }

    // scale + causal mask (lane holds S[row=quad*4+r][key=nt*16+l15])
    const int qrow = q0 + wave * 16 + quad * 4;
#pragma unroll
    for (int nt = 0; nt < 4; ++nt) {
      int key = j0 + nt * 16 + l15;
#pragma unroll
      for (int r = 0; r < 4; ++r)
        s[nt][r] = (key <= qrow + r) ? s[nt][r] * kScale : -1e30f;
    }

    // online softmax (exp2 domain), row-reduce over the 16 lanes of the quad
    float tmax[4], alpha[4], rsum[4];
#pragma unroll
    for (int r = 0; r < 4; ++r)
      tmax[r] = fmaxf(fmaxf(s[0][r], s[1][r]), fmaxf(s[2][r], s[3][r]));
#pragma unroll
    for (int off = 1; off < 16; off <<= 1)
#pragma unroll
      for (int r = 0; r < 4; ++r)
        tmax[r] = fmaxf(tmax[r], __shfl_xor(tmax[r], off, 64));
#pragma unroll
    for (int r = 0; r < 4; ++r) {
      float mn = fmaxf(m_i[r], tmax[r]);
      alpha[r] = __builtin_amdgcn_exp2f(m_i[r] - mn);
      m_i[r] = mn;
      rsum[r] = 0.f;
    }
#pragma unroll
    for (int nt = 0; nt < 4; ++nt)
#pragma unroll
      for (int r = 0; r < 4; ++r) {
        float p = __builtin_amdgcn_exp2f(s[nt][r] - m_i[r]);
        s[nt][r] = p;
        rsum[r] += p;
      }
#pragma unroll
    for (int off = 1; off < 16; off <<= 1)
#pragma unroll
      for (int r = 0; r < 4; ++r)
        rsum[r] += __shfl_xor(rsum[r], off, 64);
#pragma unroll
    for (int r = 0; r < 4; ++r)
      l_i[r] = l_i[r] * alpha[r] + rsum[r];
#pragma unroll
    for (int dt = 0; dt < 4; ++dt)
#pragma unroll
      for (int r = 0; r < 4; ++r)
        o[dt][r] *= alpha[r];

    // P: C-layout -> A-layout via LDS, swizzled like the tiles
    unsigned short* Pw = &Ps[wave][0];
    const int l15h = l15 >> 3, l15l = l15 & 7;
#pragma unroll
    for (int nt = 0; nt < 4; ++nt)
#pragma unroll
      for (int r = 0; r < 4; ++r) {
        int prow = quad * 4 + r;
        Pw[prow * 64 + ((2 * nt + l15h) ^ (prow & 7)) * 8 + l15l] = f2bf(s[nt][r]);
      }
    __syncthreads();

    s16x8 pf[2];
    pf[0] = *(const s16x8*)(Pw + l15 * 64 + ((quad    ) ^ sx) * 8);
    pf[1] = *(const s16x8*)(Pw + l15 * 64 + ((quad + 4) ^ sx) * 8);

    // O += P V : B-frag = Vt rows (contiguous b128 reads)
#pragma unroll
    for (int dt = 0; dt < 4; ++dt) {
      const int vr = dt * 16 + l15;
#pragma unroll
      for (int kk = 0; kk < 2; ++kk) {
        s16x8 vf = *(const s16x8*)(Vs + vr * 64 + ((quad + 4 * kk) ^ sx) * 8);
        o[dt] = __builtin_amdgcn_mfma_f32_16x16x32_bf16(pf[kk], vf, o[dt], 0, 0, 0);
      }
    }
  }

#pragma unroll
  for (int r = 0; r < 4; ++r)
    l_i[r] = 1.0f / l_i[r];
  const size_t yrow = (size_t)(b * 2048 + q0 + wave * 16 + quad * 4);
#pragma unroll
  for (int dt = 0; dt < 4; ++dt)
#pragma unroll
    for (int r = 0; r < 4; ++r)
      Y[(yrow + r) * 1024 + h * 64 + dt * 16 + l15] = f2bf(o[dt][r] * l_i[r]);
}

extern "C" void kernel_launch(void* const* d_in, const int* in_sizes, int n_in,
                              void* d_out, int out_size, void* d_ws, size_t ws_size,
                              hipStream_t stream) {
  const float* x      = (const float*)d_in[0];  // [2,2048,1024]
  const float* w_qkv  = (const float*)d_in[1];  // [1024,3072]
  const float* w_proj = (const float*)d_in[2];  // [1024,1024]
  char* ws = (char*)d_ws;
  unsigned short* xb     = (unsigned short*)(ws);                      //  8 MiB [4096,1024]
  unsigned short* wqkvT  = (unsigned short*)(ws + (size_t)(8  << 20)); //  6 MiB [3072,1024]
  unsigned short* wprojT = (unsigned short*)(ws + (size_t)(14 << 20)); //  2 MiB [1024,1024]
  unsigned short* qkv    = (unsigned short*)(ws + (size_t)(16 << 20)); // 24 MiB [4096,3072]
  unsigned short* y      = (unsigned short*)(ws + (size_t)(40 << 20)); //  8 MiB [4096,1024]
  unsigned short* Vt     = (unsigned short*)(ws + (size_t)(48 << 20)); //  8 MiB [32,64,2048]

  f32_to_bf16_kernel<<<4096, 256, 0, stream>>>(x, xb, 1048576);
  transpose_f32_bf16<<<dim3(96, 32), dim3(32, 8), 0, stream>>>(w_qkv, wqkvT, 1024, 3072);
  transpose_f32_bf16<<<dim3(32, 32), dim3(32, 8), 0, stream>>>(w_proj, wprojT, 1024, 1024);
  gemm_bt<true><<<dim3(24, 32), 256, 0, stream>>>(xb, wqkvT, qkv, 4096, 3072, 1024);
  transpose_v<<<dim3(32, 32), 256, 0, stream>>>(qkv, Vt);
  attn_kernel<<<dim3(32, 32), 256, 0, stream>>>(qkv, Vt, y);
  gemm_bt<false><<<dim3(8, 32), 256, 0, stream>>>(y, wprojT, d_out, 4096, 1024, 1024);
}

// Round 3
// 213.959 us; speedup vs baseline: 1.4975x; 1.2861x over previous
//
#include <hip/hip_runtime.h>

#define AS1 __attribute__((address_space(1)))
#define AS3 __attribute__((address_space(3)))

using f32x4 = __attribute__((ext_vector_type(4))) float;
using s16x8 = __attribute__((ext_vector_type(8))) short;
using u16x4 = __attribute__((ext_vector_type(4))) unsigned short;

__device__ __forceinline__ unsigned short f2bf(float f) {
  union { float f; unsigned u; } v; v.f = f;
  unsigned u = v.u;
  return (unsigned short)((u + 0x7FFFu + ((u >> 16) & 1u)) >> 16);  // RNE
}

__device__ __forceinline__ unsigned short f2bf_trunc(float f) {
  union { float f; unsigned u; } v; v.f = f;
  return (unsigned short)(v.u >> 16);  // truncate: fine for P in [0,1]
}

__device__ __forceinline__ void load_lds16(const void* g, void* l) {
  __builtin_amdgcn_global_load_lds((const AS1 void*)g, (AS3 void*)l, 16, 0, 0);
}

// ---------------- fp32 -> bf16 cast (x) ----------------
__global__ __launch_bounds__(256) void f32_to_bf16_kernel(const float* __restrict__ in,
                                                          unsigned short* __restrict__ out,
                                                          int n4) {
  int i = blockIdx.x * 256 + threadIdx.x;
  if (i < n4) {
    float4 v = ((const float4*)in)[i];
    u16x4 o;
    o.x = f2bf(v.x); o.y = f2bf(v.y); o.z = f2bf(v.z); o.w = f2bf(v.w);
    ((u16x4*)out)[i] = o;
  }
}

// ---------------- fp32 [R][C] -> bf16 [C][R] transpose (weights) ----------------
__global__ __launch_bounds__(256) void transpose_f32_bf16(const float* __restrict__ in,
                                                          unsigned short* __restrict__ out,
                                                          int R, int C) {
  __shared__ float tile[32][33];
  int x = blockIdx.x * 32 + threadIdx.x;
  int y0 = blockIdx.y * 32;
  for (int j = threadIdx.y; j < 32; j += 8)
    tile[j][threadIdx.x] = in[(size_t)(y0 + j) * C + x];
  __syncthreads();
  int x2 = blockIdx.y * 32 + threadIdx.x;
  int y2 = blockIdx.x * 32;
  for (int j = threadIdx.y; j < 32; j += 8)
    out[(size_t)(y2 + j) * R + x2] = f2bf(tile[threadIdx.x][j]);
}

// ---------------- V transpose: qkv V block [s][d] -> Vt[b][h][d][s] ----------------
__global__ __launch_bounds__(256) void transpose_v(const unsigned short* __restrict__ qkv,
                                                   unsigned short* __restrict__ Vt) {
  __shared__ unsigned short tile[64][65];
  const int tid = threadIdx.x;
  const int bh = blockIdx.y, b = bh >> 4, h = bh & 15;
  const int s0 = blockIdx.x * 64;
#pragma unroll
  for (int it = 0; it < 2; ++it) {
    int c = tid + it * 256;
    int row = c >> 3, cc = c & 7;
    s16x8 v = *(const s16x8*)(qkv + (size_t)(b * 2048 + s0 + row) * 3072 + 2048 + h * 64 + cc * 8);
#pragma unroll
    for (int j = 0; j < 8; ++j) tile[row][cc * 8 + j] = (unsigned short)v[j];
  }
  __syncthreads();
#pragma unroll
  for (int it = 0; it < 2; ++it) {
    int c = tid + it * 256;
    int d = c >> 3, sc = c & 7;
    s16x8 o;
#pragma unroll
    for (int j = 0; j < 8; ++j) o[j] = (short)tile[sc * 8 + j][d];
    *(s16x8*)(Vt + (size_t)bh * 64 * 2048 + (size_t)d * 2048 + s0 + sc * 8) = o;
  }
}

// ---------------- bf16 GEMM: C[M,N] = A[M,K] * Bt[N,K]^T (m97 structure) ----------------
template <bool OUT_BF16>
__global__ __launch_bounds__(256) void gemm_bt(const unsigned short* __restrict__ A,
                                               const unsigned short* __restrict__ Bt,
                                               void* __restrict__ Cout,
                                               int M, int N, int K) {
  __shared__ unsigned short As[128 * 32];
  __shared__ unsigned short Bs[128 * 32];
  const int tid = threadIdx.x;
  const int wave = tid >> 6, lane = tid & 63;
  const int l15 = lane & 15, quad = lane >> 4;
  const int wm = wave & 1, wn = wave >> 1;
  const int bm = blockIdx.y, bn = blockIdx.x;

  f32x4 acc[4][4] = {};

  const int c0 = wave * 128 + lane;
  for (int k0 = 0; k0 < K; k0 += 32) {
    __syncthreads();
#pragma unroll
    for (int s = 0; s < 2; ++s) {
      int c = c0 + s * 64;
      int row = c >> 2, kc = (c & 3) * 8;
      load_lds16(A + (size_t)(bm * 128 + row) * K + k0 + kc, As + c * 8);
      load_lds16(Bt + (size_t)(bn * 128 + row) * K + k0 + kc, Bs + c * 8);
    }
    __syncthreads();
    s16x8 af[4], bfr[4];
#pragma unroll
    for (int i = 0; i < 4; ++i) {
      af[i]  = *(const s16x8*)(As + (wm * 64 + i * 16 + l15) * 32 + quad * 8);
      bfr[i] = *(const s16x8*)(Bs + (wn * 64 + i * 16 + l15) * 32 + quad * 8);
    }
#pragma unroll
    for (int i = 0; i < 4; ++i)
#pragma unroll
      for (int j = 0; j < 4; ++j)
        acc[i][j] = __builtin_amdgcn_mfma_f32_16x16x32_bf16(af[i], bfr[j], acc[i][j], 0, 0, 0);
  }

  const int row0 = bm * 128 + wm * 64 + quad * 4;
  const int col0 = bn * 128 + wn * 64 + l15;
#pragma unroll
  for (int i = 0; i < 4; ++i)
#pragma unroll
    for (int j = 0; j < 4; ++j)
#pragma unroll
      for (int r = 0; r < 4; ++r) {
        size_t idx = (size_t)(row0 + i * 16 + r) * N + (col0 + j * 16);
        if constexpr (OUT_BF16) ((unsigned short*)Cout)[idx] = f2bf(acc[i][j][r]);
        else                    ((float*)Cout)[idx] = acc[i][j][r];
      }
}

// ---------------- flash attention v3 ----------------
// 128 q-rows/block, 8 waves (wave w owns rows [q0+16w, q0+16w+16)), grid 512.
// CU-balanced swizzle: blocks p and p+256 share a CU under round-robin dispatch;
// they get q-tiles lq and 15-lq -> constant 17 work-units per CU.
// LDS tiles swizzled (chunk cc of row r at physical cc^(r&7)); Qs doubles as the
// wave-private P buffer after qf is lifted to registers.
__global__ __launch_bounds__(512) void attn_kernel(const unsigned short* __restrict__ qkv,
                                                   const unsigned short* __restrict__ Vt,
                                                   unsigned short* __restrict__ Y) {
  __shared__ unsigned short Qs[128 * 64];  // Q tile, then P buffer (wave-private strips)
  __shared__ unsigned short Ks[64 * 64];
  __shared__ unsigned short Vs[64 * 64];   // Vt tile: rows = d, cols = keys
  const int tid = threadIdx.x;
  const int wave = tid >> 6, lane = tid & 63;
  const int l15 = lane & 15, quad = lane >> 4;
  const int sx = l15 & 7;

  const int p = blockIdx.x;
  const int r_ = p >> 8, c_ = p & 255;
  const int m_ = c_ & 15, g_ = c_ >> 4;
  const int bh = g_ + 16 * r_;
  const int lq = r_ ? (15 - m_) : m_;
  const int q0 = lq * 128;
  const int b = bh >> 4, h = bh & 15;
  const size_t base = (size_t)b * 2048 * 3072 + h * 64;
  const size_t vbase = (size_t)bh * 64 * 2048;

  // stage Q tile 128x64 (swizzled): 1024 chunks, 2/thread
#pragma unroll
  for (int s = 0; s < 2; ++s) {
    int cid = tid + s * 512;
    int row = cid >> 3, cc = cid & 7;
    int kc = (cc ^ (row & 7)) * 8;
    load_lds16(qkv + base + (size_t)(q0 + row) * 3072 + kc, Qs + cid * 8);
  }
  __syncthreads();
  const int qr = wave * 16 + l15;
  s16x8 qf[2];
  qf[0] = *(const s16x8*)(Qs + qr * 64 + ((quad    ) ^ sx) * 8);
  qf[1] = *(const s16x8*)(Qs + qr * 64 + ((quad + 4) ^ sx) * 8);

  f32x4 o[4] = {};
  float m_i[4] = {-1e30f, -1e30f, -1e30f, -1e30f};
  float l_i[4] = {0.f, 0.f, 0.f, 0.f};
  const float kScale = 0.125f * 1.44269504f;  // 1/sqrt(64) * log2(e)
  const int qrow_w0 = q0 + wave * 16;         // wave's first q row
  unsigned short* Pw = Qs + wave * 16 * 64;   // wave-private P strip

  for (int j0 = 0; j0 <= q0 + 64; j0 += 64) {
    __syncthreads();
    {
      int row = tid >> 3, cc = tid & 7;
      int kc = (cc ^ (row & 7)) * 8;
      load_lds16(qkv + base + (size_t)(j0 + row) * 3072 + 1024 + kc, Ks + tid * 8);
      load_lds16(Vt + vbase + (size_t)row * 2048 + j0 + kc, Vs + tid * 8);
    }
    __syncthreads();

    if (j0 <= qrow_w0 + 15) {  // wave has at least one unmasked row in this j-block
      // S = Q K^T (raw scores; scale folded into exp2 arg later)
      f32x4 s[4];
#pragma unroll
      for (int nt = 0; nt < 4; ++nt) {
        const int kr = nt * 16 + l15;
        s16x8 kf0 = *(const s16x8*)(Ks + kr * 64 + ((quad    ) ^ sx) * 8);
        s16x8 kf1 = *(const s16x8*)(Ks + kr * 64 + ((quad + 4) ^ sx) * 8);
        f32x4 z = {};
        z = __builtin_amdgcn_mfma_f32_16x16x32_bf16(qf[0], kf0, z, 0, 0, 0);
        z = __builtin_amdgcn_mfma_f32_16x16x32_bf16(qf[1], kf1, z, 0, 0, 0);
        s[nt] = z;
      }

      // causal mask only where the j-block can cross the diagonal (wave-uniform)
      if (j0 + 63 > qrow_w0) {
        const int qrow = qrow_w0 + quad * 4;
#pragma unroll
        for (int nt = 0; nt < 4; ++nt) {
          int key = j0 + nt * 16 + l15;
#pragma unroll
          for (int r = 0; r < 4; ++r)
            if (key > qrow + r) s[nt][r] = -3e38f;
        }
      }

      // online softmax, raw-score domain; p = exp2(fma(s, kScale, -m*kScale))
      float tmax[4], alpha[4], rsum[4], mk[4];
#pragma unroll
      for (int r = 0; r < 4; ++r)
        tmax[r] = fmaxf(fmaxf(s[0][r], s[1][r]), fmaxf(s[2][r], s[3][r]));
#pragma unroll
      for (int off = 1; off < 16; off <<= 1)
#pragma unroll
        for (int r = 0; r < 4; ++r)
          tmax[r] = fmaxf(tmax[r], __shfl_xor(tmax[r], off, 64));
#pragma unroll
      for (int r = 0; r < 4; ++r) {
        float mn = fmaxf(m_i[r], tmax[r]);
        alpha[r] = __builtin_amdgcn_exp2f((m_i[r] - mn) * kScale);
        m_i[r] = mn;
        mk[r] = mn * kScale;
        rsum[r] = 0.f;
      }
#pragma unroll
      for (int nt = 0; nt < 4; ++nt)
#pragma unroll
        for (int r = 0; r < 4; ++r) {
          float pv = __builtin_amdgcn_exp2f(__builtin_fmaf(s[nt][r], kScale, -mk[r]));
          s[nt][r] = pv;
          rsum[r] += pv;
        }
#pragma unroll
      for (int off = 1; off < 16; off <<= 1)
#pragma unroll
        for (int r = 0; r < 4; ++r)
          rsum[r] += __shfl_xor(rsum[r], off, 64);
#pragma unroll
      for (int r = 0; r < 4; ++r)
        l_i[r] = l_i[r] * alpha[r] + rsum[r];
#pragma unroll
      for (int dt = 0; dt < 4; ++dt)
#pragma unroll
        for (int r = 0; r < 4; ++r)
          o[dt][r] *= alpha[r];

      // P: C-layout -> A-layout via wave-private LDS strip (no barrier needed)
      const int l15h = l15 >> 3, l15l = l15 & 7;
#pragma unroll
      for (int nt = 0; nt < 4; ++nt)
#pragma unroll
        for (int r = 0; r < 4; ++r) {
          int prow = quad * 4 + r;
          Pw[prow * 64 + ((2 * nt + l15h) ^ (prow & 7)) * 8 + l15l] = f2bf_trunc(s[nt][r]);
        }

      s16x8 pf[2];
      pf[0] = *(const s16x8*)(Pw + l15 * 64 + ((quad    ) ^ sx) * 8);
      pf[1] = *(const s16x8*)(Pw + l15 * 64 + ((quad + 4) ^ sx) * 8);

      // O += P V
#pragma unroll
      for (int dt = 0; dt < 4; ++dt) {
        const int vr = dt * 16 + l15;
#pragma unroll
        for (int kk = 0; kk < 2; ++kk) {
          s16x8 vf = *(const s16x8*)(Vs + vr * 64 + ((quad + 4 * kk) ^ sx) * 8);
          o[dt] = __builtin_amdgcn_mfma_f32_16x16x32_bf16(pf[kk], vf, o[dt], 0, 0, 0);
        }
      }
    }
  }

#pragma unroll
  for (int r = 0; r < 4; ++r)
    l_i[r] = 1.0f / l_i[r];
  const size_t yrow = (size_t)(b * 2048 + qrow_w0 + quad * 4);
#pragma unroll
  for (int dt = 0; dt < 4; ++dt)
#pragma unroll
    for (int r = 0; r < 4; ++r)
      Y[(yrow + r) * 1024 + h * 64 + dt * 16 + l15] = f2bf(o[dt][r] * l_i[r]);
}

extern "C" void kernel_launch(void* const* d_in, const int* in_sizes, int n_in,
                              void* d_out, int out_size, void* d_ws, size_t ws_size,
                              hipStream_t stream) {
  const float* x      = (const float*)d_in[0];  // [2,2048,1024]
  const float* w_qkv  = (const float*)d_in[1];  // [1024,3072]
  const float* w_proj = (const float*)d_in[2];  // [1024,1024]
  char* ws = (char*)d_ws;
  unsigned short* xb     = (unsigned short*)(ws);                      //  8 MiB [4096,1024]
  unsigned short* wqkvT  = (unsigned short*)(ws + (size_t)(8  << 20)); //  6 MiB [3072,1024]
  unsigned short* wprojT = (unsigned short*)(ws + (size_t)(14 << 20)); //  2 MiB [1024,1024]
  unsigned short* qkv    = (unsigned short*)(ws + (size_t)(16 << 20)); // 24 MiB [4096,3072]
  unsigned short* y      = (unsigned short*)(ws + (size_t)(40 << 20)); //  8 MiB [4096,1024]
  unsigned short* Vt     = (unsigned short*)(ws + (size_t)(48 << 20)); //  8 MiB [32,64,2048]

  f32_to_bf16_kernel<<<4096, 256, 0, stream>>>(x, xb, 1048576);
  transpose_f32_bf16<<<dim3(96, 32), dim3(32, 8), 0, stream>>>(w_qkv, wqkvT, 1024, 3072);
  transpose_f32_bf16<<<dim3(32, 32), dim3(32, 8), 0, stream>>>(w_proj, wprojT, 1024, 1024);
  gemm_bt<true><<<dim3(24, 32), 256, 0, stream>>>(xb, wqkvT, qkv, 4096, 3072, 1024);
  transpose_v<<<dim3(32, 32), 256, 0, stream>>>(qkv, Vt);
  attn_kernel<<<512, 512, 0, stream>>>(qkv, Vt, y);
  gemm_bt<false><<<dim3(8, 32), 256, 0, stream>>>(y, wprojT, d_out, 4096, 1024, 1024);
}